// Round 1
// baseline (815.998 us; speedup 1.0000x reference)
//
#include <hip/hip_runtime.h>

// CTC forward loss. T=1024, B=128, C=256, S=64, L=129.
// One 64-lane wave per batch element. Lane i holds alpha[2i] ("a", blank state)
// and alpha[2i+1] ("b", target state tgt[i]); lane 63 also holds alpha[128] ("c").
// Even states never use the skip path (ext==0), so the only cross-lane value
// needed per step is alpha[2i-1] = b from lane i-1 -> one __shfl_up per step.
// Emit values (row[0] uniform + row[tgt_i] gather) are prefetched PF steps deep
// in registers so global latency is off the critical path.

#define NEGV (-1e30f)
#define NEGH (-5e29f)

constexpr int T_ = 1024;
constexpr int C_ = 256;
constexpr int PF = 8;   // prefetch depth (register ring)

__device__ __forceinline__ float lse2f(float x, float y) {
    float m = fmaxf(x, y);
    float s = __expf(x - m) + __expf(y - m);
    float r = m + __logf(s);
    return (m > NEGH) ? r : NEGV;
}

__device__ __forceinline__ float lse3f(float x, float y, float z) {
    float m = fmaxf(fmaxf(x, y), z);
    float s = __expf(x - m) + __expf(y - m) + __expf(z - m);
    float r = m + __logf(s);
    return (m > NEGH) ? r : NEGV;
}

__global__ __launch_bounds__(64) void ctc_alpha_kernel(
    const float* __restrict__ lp,      // (T, B, C) log-probs
    const int* __restrict__ targets,   // (B*S,)
    const int* __restrict__ in_len,    // (B,)
    const int* __restrict__ tgt_len,   // (B,)
    float* __restrict__ partial,       // (B,) per-batch loss/tl
    int B, int S)
{
    const int b = blockIdx.x;
    const int i = threadIdx.x;          // lane 0..63
    const int BC = B * C_;

    int my_tgt = (i < S) ? targets[b * S + i] : 0;
    int prev_tgt = __shfl_up(my_tgt, 1);
    const bool skip = (i > 0) && (my_tgt != prev_tgt) && (my_tgt != 0);
    const int ilen = in_len[b];

    const float* rowb = lp + (size_t)b * C_;   // row at time t: rowb + t*BC

    // t = 0 init: alpha0[0]=row0[0], alpha0[1]=row0[tgt0], rest NEG
    float r00 = rowb[0];
    float r0t = rowb[my_tgt];
    float a  = (i == 0) ? r00 : NEGV;
    float bb = (i == 0) ? r0t : NEGV;
    float c  = NEGV;                    // state 128, live on lane 63 only

    // preload emit for steps t = 1 .. PF
    float pf_bl[PF], pf_my[PF];
#pragma unroll
    for (int j = 0; j < PF; ++j) {
        int t = 1 + j;
        pf_bl[j] = (t < T_) ? rowb[(size_t)t * BC] : 0.f;
        pf_my[j] = (t < T_) ? rowb[(size_t)t * BC + my_tgt] : 0.f;
    }

    for (int tb = 1; tb < T_; tb += PF) {
#pragma unroll
        for (int j = 0; j < PF; ++j) {
            int t = tb + j;
            if (t < T_) {
                float bl = pf_bl[j];
                float ml = pf_my[j];
                int tn = t + PF;
                if (tn < T_) {
                    pf_bl[j] = rowb[(size_t)tn * BC];
                    pf_my[j] = rowb[(size_t)tn * BC + my_tgt];
                }
                float pb = __shfl_up(bb, 1);          // alpha[2i-1]
                if (i == 0) pb = NEGV;
                float na = lse2f(a, pb) + bl;                         // state 2i
                float nb = lse3f(bb, a, skip ? pb : NEGV) + ml;       // state 2i+1
                float nc = lse2f(c, bb) + bl;                         // state 128 (lane 63)
                bool act = (t < ilen);
                a  = act ? na : a;
                bb = act ? nb : bb;
                if (i == 63) c = act ? nc : c;
            }
        }
    }

    // Epilogue: gather alpha into LDS, lane 0 computes the loss
    __shared__ float sh[132];
    sh[2 * i]     = a;
    sh[2 * i + 1] = bb;
    if (i == 63) sh[128] = c;
    __syncthreads();
    if (i == 0) {
        int tl = tgt_len[b];
        int hi = 2 * tl;
        float ll = lse2f(sh[hi], sh[hi - 1]);
        float loss = (ll > NEGH) ? -ll : 0.f;
        partial[b] = loss / (float)tl;
    }
}

__global__ __launch_bounds__(128) void ctc_reduce_kernel(
    const float* __restrict__ partial, float* __restrict__ out, int B)
{
    float v = (threadIdx.x < B) ? partial[threadIdx.x] : 0.f;
#pragma unroll
    for (int off = 32; off > 0; off >>= 1)
        v += __shfl_down(v, off);       // 64-lane wave reduce
    __shared__ float ws[2];
    if ((threadIdx.x & 63) == 0) ws[threadIdx.x >> 6] = v;
    __syncthreads();
    if (threadIdx.x == 0) out[0] = (ws[0] + ws[1]) / (float)B;
}

extern "C" void kernel_launch(void* const* d_in, const int* in_sizes, int n_in,
                              void* d_out, int out_size, void* d_ws, size_t ws_size,
                              hipStream_t stream)
{
    const float* lp      = (const float*)d_in[0];  // (T,B,C) float32
    const int*   targets = (const int*)d_in[1];    // (B*S,)  int32
    const int*   il      = (const int*)d_in[2];    // (B,)
    const int*   tl      = (const int*)d_in[3];    // (B,)
    const int B = in_sizes[2];
    const int S = in_sizes[1] / B;

    float* partial = (float*)d_ws;     // B floats of scratch

    ctc_alpha_kernel<<<B, 64, 0, stream>>>(lp, targets, il, tl, partial, B, S);
    ctc_reduce_kernel<<<1, 128, 0, stream>>>(partial, (float*)d_out, B);
}

// Round 2
// 417.933 us; speedup vs baseline: 1.9525x; 1.9525x over previous
//
#include <hip/hip_runtime.h>

// CTC forward loss. T=1024, B=128, C=256, S=64, L=129.
// One 64-lane wave per batch element. Lane i holds alpha[2i] ("a", blank state)
// and alpha[2i+1] ("bb", target state tgt[i]); lane 63 also holds alpha[128] ("c").
// Even states never use the skip path (ext==0), so the only cross-lane value
// needed per step is alpha[2i-1] = bb from lane i-1 -> one DPP wave_shr:1
// (pure VALU, no LDS) per step. Emit values (row[0] uniform + row[tgt_i]
// gather) are prefetched PF=16 steps deep in registers; the main loop is
// fully branch-free (t=1..1024, step 1024 masked off by act) so the compiler
// can keep all 32 refill loads in flight.

#define NEGV (-1e30f)
#define NEGH (-5e29f)

constexpr int T_ = 1024;
constexpr int C_ = 256;
constexpr int PF = 16;   // prefetch depth (register ring)

__device__ __forceinline__ float lse2f(float x, float y) {
    float m = fmaxf(x, y);
    float s = __expf(x - m) + __expf(y - m);
    float r = m + __logf(s);
    return (m > NEGH) ? r : NEGV;
}

__device__ __forceinline__ float lse3f(float x, float y, float z) {
    float m = fmaxf(fmaxf(x, y), z);
    float s = __expf(x - m) + __expf(y - m) + __expf(z - m);
    float r = m + __logf(s);
    return (m > NEGH) ? r : NEGV;
}

// lane i gets x from lane i-1; lane 0 gets `fill`. DPP wave_shr:1 — VALU only.
__device__ __forceinline__ float wave_shr1(float x, float fill) {
    int r = __builtin_amdgcn_update_dpp(__float_as_int(fill), __float_as_int(x),
                                        0x138 /*wave_shr:1*/, 0xf, 0xf, false);
    return __int_as_float(r);
}

__global__ __launch_bounds__(64) void ctc_alpha_kernel(
    const float* __restrict__ lp,      // (T, B, C) log-probs
    const int* __restrict__ targets,   // (B*S,)
    const int* __restrict__ in_len,    // (B,)
    const int* __restrict__ tgt_len,   // (B,)
    float* __restrict__ partial,       // (B,) per-batch loss/tl
    int B, int S)
{
    const int b = blockIdx.x;
    const int i = threadIdx.x;          // lane 0..63
    const int BC = B * C_;

    int my_tgt = (i < S) ? targets[b * S + i] : 0;
    int prev_tgt = __shfl_up(my_tgt, 1);
    const bool skip = (i > 0) && (my_tgt != prev_tgt) && (my_tgt != 0);
    const int ilen = in_len[b];

    const float* rowb = lp + (size_t)b * C_;   // row at time t: rowb + t*BC

    // t = 0 init: alpha0[0]=row0[0], alpha0[1]=row0[tgt0], rest NEG
    float r00 = rowb[0];
    float r0t = rowb[my_tgt];
    float a  = (i == 0) ? r00 : NEGV;
    float bb = (i == 0) ? r0t : NEGV;
    float c  = NEGV;                    // state 128, live on lane 63 only

    // preload emit for steps t = 1 .. PF
    float pf_bl[PF], pf_my[PF];
#pragma unroll
    for (int j = 0; j < PF; ++j) {
        int t = 1 + j;
        pf_bl[j] = rowb[(size_t)t * BC];
        pf_my[j] = rowb[(size_t)t * BC + my_tgt];
    }

    // 64 outer iterations x 16 steps = t = 1 .. 1024 (step 1024 is a masked
    // no-op: act=false since ilen <= 1024; its prefetch clamps to row 1023).
    for (int tb = 1; tb < 1 + T_; tb += PF) {
#pragma unroll
        for (int j = 0; j < PF; ++j) {
            int t = tb + j;
            float bl = pf_bl[j];
            float ml = pf_my[j];
            int tn = t + PF;
            tn = (tn > T_ - 1) ? (T_ - 1) : tn;   // clamp, branch-free
            const float* rt = rowb + (size_t)tn * BC;
            pf_bl[j] = rt[0];
            pf_my[j] = rt[my_tgt];
            float pb = wave_shr1(bb, NEGV);       // alpha[2i-1]
            float na = lse2f(a, pb) + bl;                         // state 2i
            float nb = lse3f(bb, a, skip ? pb : NEGV) + ml;       // state 2i+1
            float nc = lse2f(c, bb) + bl;                         // state 128
            bool act = (t < ilen);
            a  = act ? na : a;
            bb = act ? nb : bb;
            if (i == 63) c = act ? nc : c;
        }
    }

    // Epilogue: gather alpha into LDS, lane 0 computes the loss
    __shared__ float sh[132];
    sh[2 * i]     = a;
    sh[2 * i + 1] = bb;
    if (i == 63) sh[128] = c;
    __syncthreads();
    if (i == 0) {
        int tl = tgt_len[b];
        int hi = 2 * tl;
        float ll = lse2f(sh[hi], sh[hi - 1]);
        float loss = (ll > NEGH) ? -ll : 0.f;
        partial[b] = loss / (float)tl;
    }
}

__global__ __launch_bounds__(128) void ctc_reduce_kernel(
    const float* __restrict__ partial, float* __restrict__ out, int B)
{
    float v = (threadIdx.x < B) ? partial[threadIdx.x] : 0.f;
#pragma unroll
    for (int off = 32; off > 0; off >>= 1)
        v += __shfl_down(v, off);       // 64-lane wave reduce
    __shared__ float ws[2];
    if ((threadIdx.x & 63) == 0) ws[threadIdx.x >> 6] = v;
    __syncthreads();
    if (threadIdx.x == 0) out[0] = (ws[0] + ws[1]) / (float)B;
}

extern "C" void kernel_launch(void* const* d_in, const int* in_sizes, int n_in,
                              void* d_out, int out_size, void* d_ws, size_t ws_size,
                              hipStream_t stream)
{
    const float* lp      = (const float*)d_in[0];  // (T,B,C) float32
    const int*   targets = (const int*)d_in[1];    // (B*S,)  int32
    const int*   il      = (const int*)d_in[2];    // (B,)
    const int*   tl      = (const int*)d_in[3];    // (B,)
    const int B = in_sizes[2];
    const int S = in_sizes[1] / B;

    float* partial = (float*)d_ws;     // B floats of scratch

    ctc_alpha_kernel<<<B, 64, 0, stream>>>(lp, targets, il, tl, partial, B, S);
    ctc_reduce_kernel<<<1, 128, 0, stream>>>(partial, (float*)d_out, B);
}

// Round 3
// 349.360 us; speedup vs baseline: 2.3357x; 1.1963x over previous
//
#include <hip/hip_runtime.h>

// CTC forward loss. T=1024, B=128, C=256, S=64, L=129.
// Producer/consumer block: 2 waves per batch element.
//   wave 1 streams full 1KB rows lp[t][b][:] into a 2x32-row LDS ring with
//          global_load_lds (16B/lane, 1 instr/row, no VGPR round trip);
//   wave 0 runs the alpha recurrence, reading emit values from LDS.
// Lane i of wave 0 holds alpha[2i] ("a") and alpha[2i+1] ("bb"); lane 63 also
// holds alpha[128] ("c"). Only cross-lane value needed per step is
// alpha[2i-1] -> DPP wave_shr:1 (pure VALU). One __syncthreads per 32-step
// chunk; its implicit vmcnt(0) drain is the producer completion guarantee.

#define NEGV (-1e30f)
#define NEGH (-5e29f)

constexpr int T_  = 1024;
constexpr int C_  = 256;
constexpr int CH  = 32;        // rows per chunk
constexpr int NCH = T_ / CH;   // 32 chunks covering t = 1 .. 1024

__device__ __forceinline__ float lse2f(float x, float y) {
    float m = fmaxf(x, y);
    float s = __expf(x - m) + __expf(y - m);
    float r = m + __logf(s);
    return (m > NEGH) ? r : NEGV;
}

__device__ __forceinline__ float lse3f(float x, float y, float z) {
    float m = fmaxf(fmaxf(x, y), z);
    float s = __expf(x - m) + __expf(y - m) + __expf(z - m);
    float r = m + __logf(s);
    return (m > NEGH) ? r : NEGV;
}

// lane i gets x from lane i-1; lane 0 gets `fill`. DPP wave_shr:1 — VALU only.
__device__ __forceinline__ float wave_shr1(float x, float fill) {
    int r = __builtin_amdgcn_update_dpp(__float_as_int(fill), __float_as_int(x),
                                        0x138 /*wave_shr:1*/, 0xf, 0xf, false);
    return __int_as_float(r);
}

__global__ __launch_bounds__(128) void ctc_alpha_kernel(
    const float* __restrict__ lp,      // (T, B, C) log-probs
    const int* __restrict__ targets,   // (B*S,)
    const int* __restrict__ in_len,    // (B,)
    const int* __restrict__ tgt_len,   // (B,)
    float* __restrict__ partial,       // (B,) per-batch loss/tl
    int B, int S)
{
    __shared__ float rows[2][CH][C_];  // 64 KiB double-buffered row ring
    __shared__ float sh[132];

    const int b    = blockIdx.x;
    const int tid  = threadIdx.x;
    const int wave = tid >> 6;
    const int lane = tid & 63;
    const int BC   = B * C_;
    const float* rowb = lp + (size_t)b * C_;   // row at time t: rowb + t*BC

    // per-lane consumer state (computed by all, used by wave 0)
    int my_tgt = (lane < S) ? targets[b * S + lane] : 0;
    int prev_tgt = __shfl_up(my_tgt, 1);
    const bool skip = (lane > 0) && (my_tgt != prev_tgt) && (my_tgt != 0);
    const int ilen = in_len[b];

    float a = NEGV, bb = NEGV, c = NEGV;
    if (wave == 0) {
        // t = 0 init: alpha0[0]=row0[0], alpha0[1]=row0[tgt0], rest NEG
        float r00 = rowb[0];
        float r0t = rowb[my_tgt];
        a  = (lane == 0) ? r00 : NEGV;
        bb = (lane == 0) ? r0t : NEGV;
    }

    const float* gl = rowb + lane * 4;         // 16 B per lane within a row

    // producer prefill: chunk 0 = rows t = 1 .. CH into buffer 0
    if (wave == 1) {
#pragma unroll
        for (int r = 0; r < CH; ++r) {
            __builtin_amdgcn_global_load_lds(
                (const __attribute__((address_space(1))) void*)(gl + (size_t)(1 + r) * BC),
                (__attribute__((address_space(3))) void*)&rows[0][r][0],
                16, 0, 0);
        }
    }
    __syncthreads();   // implicit vmcnt(0): chunk 0 resident

    for (int k = 0; k < NCH; ++k) {
        if (wave == 1) {
            // stream chunk k+1 into the other buffer
            if (k + 1 < NCH) {
                const int nb = (k + 1) & 1;
                const int t0 = 1 + (k + 1) * CH;
#pragma unroll
                for (int r = 0; r < CH; ++r) {
                    int t = t0 + r;
                    t = (t > T_ - 1) ? (T_ - 1) : t;   // t=1024 row is unused; clamp
                    __builtin_amdgcn_global_load_lds(
                        (const __attribute__((address_space(1))) void*)(gl + (size_t)t * BC),
                        (__attribute__((address_space(3))) void*)&rows[nb][r][0],
                        16, 0, 0);
                }
            }
        } else {
            // consume chunk k: steps t = 1+k*CH .. CH+k*CH (t=1024 masked by act)
            const int buf = k & 1;
            const int t0  = 1 + k * CH;
#pragma unroll
            for (int r = 0; r < CH; ++r) {
                const int t = t0 + r;
                float bl = rows[buf][r][0];        // blank emit (broadcast read)
                float ml = rows[buf][r][my_tgt];   // target emit (gather)
                float pb = wave_shr1(bb, NEGV);    // alpha[2i-1]
                float na  = lse2f(a, pb) + bl;                      // state 2i
                float nb_ = lse3f(bb, a, skip ? pb : NEGV) + ml;    // state 2i+1
                float nc  = lse2f(c, bb) + bl;                      // state 128
                bool act = (t < ilen);
                a  = act ? na  : a;
                bb = act ? nb_ : bb;
                if (lane == 63) c = act ? nc : c;
            }
        }
        __syncthreads();   // chunk boundary: producer drained, buffers swap
    }

    // Epilogue: gather alpha into LDS, thread 0 computes the loss
    if (wave == 0) {
        sh[2 * lane]     = a;
        sh[2 * lane + 1] = bb;
        if (lane == 63) sh[128] = c;
    }
    __syncthreads();
    if (tid == 0) {
        int tl = tgt_len[b];
        int hi = 2 * tl;
        float ll = lse2f(sh[hi], sh[hi - 1]);
        float loss = (ll > NEGH) ? -ll : 0.f;
        partial[b] = loss / (float)tl;
    }
}

__global__ __launch_bounds__(128) void ctc_reduce_kernel(
    const float* __restrict__ partial, float* __restrict__ out, int B)
{
    float v = 0.f;
    for (int j = threadIdx.x; j < B; j += 128) v += partial[j];
#pragma unroll
    for (int off = 32; off > 0; off >>= 1)
        v += __shfl_down(v, off);       // 64-lane wave reduce
    __shared__ float ws[2];
    if ((threadIdx.x & 63) == 0) ws[threadIdx.x >> 6] = v;
    __syncthreads();
    if (threadIdx.x == 0) out[0] = (ws[0] + ws[1]) / (float)B;
}

extern "C" void kernel_launch(void* const* d_in, const int* in_sizes, int n_in,
                              void* d_out, int out_size, void* d_ws, size_t ws_size,
                              hipStream_t stream)
{
    const float* lp      = (const float*)d_in[0];  // (T,B,C) float32
    const int*   targets = (const int*)d_in[1];    // (B*S,)  int32
    const int*   il      = (const int*)d_in[2];    // (B,)
    const int*   tl      = (const int*)d_in[3];    // (B,)
    const int B = in_sizes[2];
    const int S = in_sizes[1] / B;

    float* partial = (float*)d_ws;     // B floats of scratch

    ctc_alpha_kernel<<<B, 128, 0, stream>>>(lp, targets, il, tl, partial, B, S);
    ctc_reduce_kernel<<<1, 128, 0, stream>>>(partial, (float*)d_out, B);
}

// Round 4
// 217.921 us; speedup vs baseline: 3.7445x; 1.6031x over previous
//
#include <hip/hip_runtime.h>

// CTC forward loss. T=1024, B=128, C=256, S=64, L=129.
// Producer/consumer block (2 waves per batch element):
//   wave 1 streams full 1KB rows lp[t][b][:] into a 2x32-row LDS ring with
//          global_load_lds (16B/lane, 1 instr/row, no VGPR round trip);
//   wave 0 runs the alpha recurrence in SCALED LINEAR space:
//     p_i = exp(alpha_i) * 2^es  (es = wave-uniform int exponent)
//     step: p_a' = (p_a + pb)*exp(bl); p_b' = (p_b + p_a + skip*pb)*exp(ml);
//           p_c' = (p_c + p_b)*exp(bl)   [lane 63 holds state 128]
//   -> no transcendentals on the critical chain (exp(emit) is off-chain).
//   Every 8 steps: DPP wave-max, readlane, exponent extract, exact ldexp
//   rescale by 2^-e, es += e. Rescale is value-preserving, so act-frozen
//   states stay correct. Cross-lane alpha[2i-1] via DPP wave_shr:1.

#define NEGV (-1e30f)
#define NEGH (-5e29f)

constexpr int T_  = 1024;
constexpr int C_  = 256;
constexpr int CH  = 32;        // rows per chunk
constexpr int NCH = T_ / CH;   // 32 chunks covering t = 1 .. 1024

__device__ __forceinline__ float lse2f(float x, float y) {
    float m = fmaxf(x, y);
    float s = __expf(x - m) + __expf(y - m);
    float r = m + __logf(s);
    return (m > NEGH) ? r : NEGV;
}

// lane i gets x from lane i-1; lane 0 gets `fill`. DPP wave_shr:1 — VALU only.
__device__ __forceinline__ float wave_shr1(float x, float fill) {
    int r = __builtin_amdgcn_update_dpp(__float_as_int(fill), __float_as_int(x),
                                        0x138 /*wave_shr:1*/, 0xf, 0xf, false);
    return __int_as_float(r);
}

// one step of a DPP max-reduction; old = x is the identity under fmax
template <int CTRL>
__device__ __forceinline__ float dpp_maxstep(float x) {
    int r = __builtin_amdgcn_update_dpp(__float_as_int(x), __float_as_int(x),
                                        CTRL, 0xf, 0xf, false);
    return fmaxf(x, __int_as_float(r));
}

__global__ __launch_bounds__(128) void ctc_alpha_kernel(
    const float* __restrict__ lp,      // (T, B, C) log-probs
    const int* __restrict__ targets,   // (B*S,)
    const int* __restrict__ in_len,    // (B,)
    const int* __restrict__ tgt_len,   // (B,)
    float* __restrict__ partial,       // (B,) per-batch loss/tl
    int B, int S)
{
    __shared__ float rows[2][CH][C_];  // 64 KiB double-buffered row ring
    __shared__ float sh[132];

    const int b    = blockIdx.x;
    const int tid  = threadIdx.x;
    const int wave = tid >> 6;
    const int lane = tid & 63;
    const int BC   = B * C_;
    const float* rowb = lp + (size_t)b * C_;   // row at time t: rowb + t*BC

    int my_tgt = (lane < S) ? targets[b * S + lane] : 0;
    int prev_tgt = __shfl_up(my_tgt, 1);
    const bool skip = (lane > 0) && (my_tgt != prev_tgt) && (my_tgt != 0);
    const int ilen = in_len[b];

    // linear-domain state: p = exp(alpha) * 2^es
    float pa = 0.f, pb_ = 0.f, pc = 0.f;
    int es = 0;
    if (wave == 0 && lane == 0) {
        pa  = __expf(rowb[0]);        // alpha0[0] = row0[0]
        pb_ = __expf(rowb[my_tgt]);   // alpha0[1] = row0[tgt0]
    }

    const float* gl = rowb + lane * 4;         // 16 B per lane within a row

    // producer prefill: chunk 0 = rows t = 1 .. CH into buffer 0
    if (wave == 1) {
#pragma unroll
        for (int r = 0; r < CH; ++r) {
            __builtin_amdgcn_global_load_lds(
                (const __attribute__((address_space(1))) void*)(gl + (size_t)(1 + r) * BC),
                (__attribute__((address_space(3))) void*)&rows[0][r][0],
                16, 0, 0);
        }
    }
    __syncthreads();   // implicit vmcnt(0): chunk 0 resident

    for (int k = 0; k < NCH; ++k) {
        if (wave == 1) {
            if (k + 1 < NCH) {
                const int nb = (k + 1) & 1;
                const int t0 = 1 + (k + 1) * CH;
#pragma unroll
                for (int r = 0; r < CH; ++r) {
                    int t = t0 + r;
                    t = (t > T_ - 1) ? (T_ - 1) : t;   // t=1024 row unused; clamp
                    __builtin_amdgcn_global_load_lds(
                        (const __attribute__((address_space(1))) void*)(gl + (size_t)t * BC),
                        (__attribute__((address_space(3))) void*)&rows[nb][r][0],
                        16, 0, 0);
                }
            }
        } else {
            const int buf = k & 1;
            const int t0  = 1 + k * CH;
#pragma unroll
            for (int r = 0; r < CH; ++r) {
                const int t = t0 + r;
                float ebl = __expf(rows[buf][r][0]);        // off-chain
                float eml = __expf(rows[buf][r][my_tgt]);   // off-chain (gather)
                float pprev = wave_shr1(pb_, 0.f);          // p[2i-1]
                float na = (pa + pprev) * ebl;                          // state 2i
                float nb_ = (pb_ + pa + (skip ? pprev : 0.f)) * eml;    // state 2i+1
                float nc = (pc + pb_) * ebl;                            // state 128
                bool act = (t < ilen);
                pa  = act ? na  : pa;
                pb_ = act ? nb_ : pb_;
                pc  = act ? nc  : pc;   // only lane 63's pc is meaningful
                if ((r & 7) == 7) {
                    // wave-uniform rescale: exact power-of-2, value-preserving
                    float m = fmaxf(fmaxf(pa, pb_), pc);
                    m = dpp_maxstep<0x111>(m);   // row_shr:1
                    m = dpp_maxstep<0x112>(m);   // row_shr:2
                    m = dpp_maxstep<0x114>(m);   // row_shr:4
                    m = dpp_maxstep<0x118>(m);   // row_shr:8
                    m = dpp_maxstep<0x142>(m);   // row_bcast:15
                    m = dpp_maxstep<0x143>(m);   // row_bcast:31
                    float mv = __int_as_float(
                        __builtin_amdgcn_readlane(__float_as_int(m), 63));
                    int e = ((__float_as_int(mv) >> 23) & 0xff) - 127; // ilogb
                    pa  = ldexpf(pa,  -e);
                    pb_ = ldexpf(pb_, -e);
                    pc  = ldexpf(pc,  -e);
                    es += e;
                }
            }
        }
        __syncthreads();   // chunk boundary: producer drained, buffers swap
    }

    // Epilogue: back to log space, lane 0 computes the loss
    if (wave == 0) {
        const float ls = (float)es * 0.69314718055994531f;
        sh[2 * lane]     = __logf(pa)  + ls;   // log(0) = -inf handled below
        sh[2 * lane + 1] = __logf(pb_) + ls;
        if (lane == 63) sh[128] = __logf(pc) + ls;
    }
    __syncthreads();
    if (tid == 0) {
        int tl = tgt_len[b];
        int hi = 2 * tl;
        float ll = lse2f(sh[hi], sh[hi - 1]);
        float loss = (ll > NEGH) ? -ll : 0.f;
        partial[b] = loss / (float)tl;
    }
}

__global__ __launch_bounds__(128) void ctc_reduce_kernel(
    const float* __restrict__ partial, float* __restrict__ out, int B)
{
    float v = 0.f;
    for (int j = threadIdx.x; j < B; j += 128) v += partial[j];
#pragma unroll
    for (int off = 32; off > 0; off >>= 1)
        v += __shfl_down(v, off);       // 64-lane wave reduce
    __shared__ float ws[2];
    if ((threadIdx.x & 63) == 0) ws[threadIdx.x >> 6] = v;
    __syncthreads();
    if (threadIdx.x == 0) out[0] = (ws[0] + ws[1]) / (float)B;
}

extern "C" void kernel_launch(void* const* d_in, const int* in_sizes, int n_in,
                              void* d_out, int out_size, void* d_ws, size_t ws_size,
                              hipStream_t stream)
{
    const float* lp      = (const float*)d_in[0];  // (T,B,C) float32
    const int*   targets = (const int*)d_in[1];    // (B*S,)  int32
    const int*   il      = (const int*)d_in[2];    // (B,)
    const int*   tl      = (const int*)d_in[3];    // (B,)
    const int B = in_sizes[2];
    const int S = in_sizes[1] / B;

    float* partial = (float*)d_ws;     // B floats of scratch

    ctc_alpha_kernel<<<B, 128, 0, stream>>>(lp, targets, il, tl, partial, B, S);
    ctc_reduce_kernel<<<1, 128, 0, stream>>>(partial, (float*)d_out, B);
}